// Round 17
// baseline (132.195 us; speedup 1.0000x reference)
//
#include <hip/hip_runtime.h>
#include <float.h>

// KMeans assign: N=262144, K=1024, D=64, fp32 in, int32 argmin out.
// Round 17: round-16 (32x32x16 MFMA on the r8 structure) with the compile
// fix: pass FragU::b (bf16x8) to the builtin, not the union. Rationale
// unchanged: work reduction, not scheduling (10 scheduling nulls r7-r15):
// -13% matrix-pipe cycles (33.8 vs 2x19.4 cyc/SIMD per 32k FLOP), -50% MFMA
// instruction count, full-K dists per lane -> merge = one shfl_xor(32).
// A/B layout assumed row|col=lane&31, k=8*(lane>>5); C/D verified (m74/m101).
// Numerics frozen (absmax=0): OFFC=32, TAU=0.05, key-packed argmin,
// sign-check self-flag, refine2 wave-per-point exact fp32.

#define N_PTS 262144
#define K_CTR 1024
#define DIM   64
#define CTILE 64          // centers per tile; 16 tiles; dbuf: 2x(8+8) KiB
#define NTILE (K_CTR / CTILE)
#define OFFC  32.0f
#define TAU_DIST 0.05f

// ws byte offsets
#define WS_CN    0          // f32[1024]
#define WS_CI    4096       // f32[1024]  cninit = -cn/2 - OFFC
#define WS_HI    8192       // ushort[8192*8]  frag-major hi  (128 KiB)
#define WS_LO    139264     // ushort[8192*8]  frag-major lo  (128 KiB)
#define WS_CTR   270336     // int counter
#define WS_LIST  270592     // int list[...]
#define WS_MIN   (270592 + 4 * 65536)

typedef __attribute__((ext_vector_type(8)))  short  short8;
typedef __attribute__((ext_vector_type(8)))  __bf16 bf16x8;
typedef __attribute__((ext_vector_type(4)))  float  f32x4;
typedef __attribute__((ext_vector_type(16))) float  f32x16;

union FragU { short8 s; bf16x8 b; unsigned short u[8]; };

static __device__ __forceinline__ unsigned short bfbits(__bf16 h) {
    return __builtin_bit_cast(unsigned short, h);
}

#if defined(__has_builtin)
#if __has_builtin(__builtin_amdgcn_global_load_lds)
#define HAVE_GLD 1
#endif
#endif

#ifdef HAVE_GLD
#define GLD16(gsrc, ldst)                                                      \
    __builtin_amdgcn_global_load_lds(                                          \
        (const __attribute__((address_space(1))) void*)(gsrc),                 \
        (__attribute__((address_space(3))) void*)(ldst), 16, 0, 0)
#endif

// ---------------- prep: centers_norm (round-1 chain), cninit, counter=0 -----
__global__ void prep_kernel(const float* __restrict__ centers,
                            float* __restrict__ cn, float* __restrict__ ci,
                            int* __restrict__ counter) {
    int k = blockIdx.x * 256 + threadIdx.x;
    if (k == 0) *counter = 0;
    if (k < K_CTR) {
        const float4* c = reinterpret_cast<const float4*>(centers + (size_t)k * DIM);
        float s0 = 0.f, s1 = 0.f, s2 = 0.f, s3 = 0.f;
#pragma unroll
        for (int j = 0; j < 16; ++j) {
            float4 v = c[j];
            s0 = fmaf(v.x, v.x, s0); s1 = fmaf(v.y, v.y, s1);
            s2 = fmaf(v.z, v.z, s2); s3 = fmaf(v.w, v.w, s3);
        }
        float n = (s0 + s1) + (s2 + s3);
        cn[k] = n;
        ci[k] = fmaf(-0.5f, n, -OFFC);
    }
}

// ---------------- split: centers -> 32x32-frag-major bf16 hi/lo (once) ------
// slot si in [0,8192): lane=si&63, ks=(si>>6)&3, ct=si>>8 (32-center group);
// center row = ct*32 + (lane&31); dims = ks*16 + ((lane>>5)&1)*8 .. +8.
// (A-frag layout for 32x32x16: row=lane&31, k = 8*(lane>>5) within K=16.)
__global__ void split_kernel(const float* __restrict__ centers,
                             unsigned short* __restrict__ hiG,
                             unsigned short* __restrict__ loG) {
    int si = blockIdx.x * 256 + threadIdx.x;   // 8192 total
    int lane = si & 63, ks = (si >> 6) & 3, ct = si >> 8;
    int row = ct * 32 + (lane & 31);
    int dimb = ks * 16 + ((lane >> 5) & 1) * 8;
    const float* g = centers + (size_t)row * DIM + dimb;
    float4 v0 = *reinterpret_cast<const float4*>(g);
    float4 v1 = *reinterpret_cast<const float4*>(g + 4);
    float vv[8] = {v0.x, v0.y, v0.z, v0.w, v1.x, v1.y, v1.z, v1.w};
    FragU hi, lo;
#pragma unroll
    for (int j = 0; j < 8; ++j) {
        __bf16 h = (__bf16)vv[j];
        hi.u[j] = bfbits(h);
        lo.u[j] = bfbits((__bf16)(vv[j] - (float)h));
    }
    *reinterpret_cast<short8*>(hiG + (size_t)si * 8) = hi.s;
    *reinterpret_cast<short8*>(loG + (size_t)si * 8) = lo.s;
}

// ---------------- main: 32x32x16 MFMA assign, pipelined double-buffer -------
__launch_bounds__(256, 2)
__global__ void assign_mfma(const float* __restrict__ x,
                            const unsigned short* __restrict__ hiG,
                            const unsigned short* __restrict__ loG,
                            const float* __restrict__ ci,
                            int* __restrict__ out,
                            int* __restrict__ counter,
                            int* __restrict__ list, int cap) {
    __shared__ __align__(16) unsigned short lh[2 * 512 * 8];  // 16 KiB (2 buf)
    __shared__ __align__(16) unsigned short ll[2 * 512 * 8];  // 16 KiB (2 buf)
    __shared__ __align__(16) float ciL[K_CTR];                // 4 KiB

    const int tid  = threadIdx.x;
    const int wv   = tid >> 6;
    const int lane = tid & 63;
    const int col  = lane & 31;       // point column within a 32-block
    const int khalf = lane >> 5;      // k-half (0/1) of each K=16 step
    const int hi4  = khalf * 4;       // C/D row offset component
    const int pbase = blockIdx.x * 256 + wv * 64;

#pragma unroll
    for (int j = 0; j < 4; ++j) ciL[j * 256 + tid] = ci[j * 256 + tid];

    // B fragments (points): bf16 hi/lo, [pointblock pb][kstep ks]
    // B layout: col=lane&31, k = ks*16 + 8*(lane>>5) + [0..8)
    bf16x8 bh[2][4], bl[2][4];
#pragma unroll
    for (int pb = 0; pb < 2; ++pb) {
        const int p = pbase + pb * 32 + col;
        const float* xr = x + (size_t)p * DIM + khalf * 8;
#pragma unroll
        for (int ks = 0; ks < 4; ++ks) {
            float4 v0 = *reinterpret_cast<const float4*>(xr + ks * 16);
            float4 v1 = *reinterpret_cast<const float4*>(xr + ks * 16 + 4);
            float vv[8] = {v0.x, v0.y, v0.z, v0.w, v1.x, v1.y, v1.z, v1.w};
#pragma unroll
            for (int j = 0; j < 8; ++j) {
                __bf16 hb = (__bf16)vv[j];
                bh[pb][ks][j] = hb;
                bl[pb][ks][j] = (__bf16)(vv[j] - (float)hb);
            }
        }
    }

    unsigned int best[2], sec[2];
#pragma unroll
    for (int pb = 0; pb < 2; ++pb) { best[pb] = 0xFFFFFFFFu; sec[pb] = 0xFFFFFFFFu; }

    // ---- staging helper: 512 hi + 512 lo slots per tile, 2+2 GLD16/thread
#define STAGE(buf, tile)                                                       \
    do {                                                                       \
        const size_t sb = (size_t)((tile) * 512 + wv * 64 + lane) * 8;         \
        unsigned short* dh = lh + ((buf) * 512 + wv * 64) * 8;                 \
        unsigned short* dl = ll + ((buf) * 512 + wv * 64) * 8;                 \
        GLD16(hiG + sb, dh);                                                   \
        GLD16(hiG + sb + 256 * 8, dh + 256 * 8);                               \
        GLD16(loG + sb, dl);                                                   \
        GLD16(loG + sb + 256 * 8, dl + 256 * 8);                               \
    } while (0)

#ifndef HAVE_GLD
#undef STAGE
#define STAGE(buf, tile)                                                       \
    do {                                                                       \
        const short8* hs = reinterpret_cast<const short8*>(hiG) + (tile) * 512; \
        const short8* ls = reinterpret_cast<const short8*>(loG) + (tile) * 512; \
        short8* hd = reinterpret_cast<short8*>(lh) + (buf) * 512;              \
        short8* ld = reinterpret_cast<short8*>(ll) + (buf) * 512;              \
        hd[tid] = hs[tid]; hd[256 + tid] = hs[256 + tid];                      \
        ld[tid] = ls[tid]; ld[256 + tid] = ls[256 + tid];                      \
    } while (0)
#endif

    // prologue: stage tile 0 into buf 0
    STAGE(0, 0);
    __syncthreads();

    int cur = 0;
#pragma unroll 1
    for (int tile = 0; tile < NTILE; ++tile) {
        if (tile < NTILE - 1) STAGE(cur ^ 1, tile + 1);   // issue BEFORE compute

        const char* lhb = (const char*)lh + cur * 8192 + lane * 16;
        const char* llb = (const char*)ll + cur * 8192 + lane * 16;

#pragma unroll
        for (int gi = 0; gi < 2; ++gi) {                  // 32-center groups
            const int ctbase = tile * CTILE + gi * 32;

            FragU Ah[4], Al[4];
#pragma unroll
            for (int ks = 0; ks < 4; ++ks) {
                Ah[ks].s = *reinterpret_cast<const short8*>(lhb + gi * 4096 + ks * 1024);
                Al[ks].s = *reinterpret_cast<const short8*>(llb + gi * 4096 + ks * 1024);
            }

            // C-init at the 32x32 C/D layout: row = (r&3)+8*(r>>2)+hi4
            f32x16 init;
#pragma unroll
            for (int q = 0; q < 4; ++q) {
                f32x4 iq = *reinterpret_cast<const f32x4*>(ciL + ctbase + q * 8 + hi4);
#pragma unroll
                for (int j = 0; j < 4; ++j) init[q * 4 + j] = iq[j];
            }

            f32x16 acc[2];
            __builtin_amdgcn_s_setprio(1);
#pragma unroll
            for (int pb = 0; pb < 2; ++pb)
                acc[pb] = __builtin_amdgcn_mfma_f32_32x32x16_bf16(Ah[0].b, bh[pb][0], init, 0, 0, 0);
#pragma unroll
            for (int ks = 1; ks < 4; ++ks)
#pragma unroll
                for (int pb = 0; pb < 2; ++pb)
                    acc[pb] = __builtin_amdgcn_mfma_f32_32x32x16_bf16(Ah[ks].b, bh[pb][ks], acc[pb], 0, 0, 0);
#pragma unroll
            for (int ks = 0; ks < 4; ++ks)
#pragma unroll
                for (int pb = 0; pb < 2; ++pb)
                    acc[pb] = __builtin_amdgcn_mfma_f32_32x32x16_bf16(Ah[ks].b, bl[pb][ks], acc[pb], 0, 0, 0);
#pragma unroll
            for (int ks = 0; ks < 4; ++ks)
#pragma unroll
                for (int pb = 0; pb < 2; ++pb)
                    acc[pb] = __builtin_amdgcn_mfma_f32_32x32x16_bf16(Al[ks].b, bh[pb][ks], acc[pb], 0, 0, 0);
            __builtin_amdgcn_s_setprio(0);

#pragma unroll
            for (int pb = 0; pb < 2; ++pb) {
#pragma unroll
                for (int q = 0; q < 4; ++q) {
                    const unsigned int kb0 = (unsigned int)(ctbase + q * 8 + hi4);
#pragma unroll
                    for (int pr = 0; pr < 2; ++pr) {
                        unsigned int ka = (__float_as_uint(acc[pb][q * 4 + pr * 2 + 0]) & 0xFFFFFC00u) | (kb0 + pr * 2 + 0);
                        unsigned int kb = (__float_as_uint(acc[pb][q * 4 + pr * 2 + 1]) & 0xFFFFFC00u) | (kb0 + pr * 2 + 1);
                        unsigned int bo = best[pb], med, bn;
                        asm("v_med3_u32 %0, %1, %2, %3" : "=v"(med) : "v"(ka), "v"(kb), "v"(bo));
                        asm("v_min3_u32 %0, %1, %2, %3" : "=v"(bn)  : "v"(ka), "v"(kb), "v"(bo));
                        best[pb] = bn;
                        sec[pb]  = min(sec[pb], med);
                    }
                }
            }
        }

        __syncthreads();   // vmcnt(0)+barrier: stage(tile+1) landed, buf[cur] free
        cur ^= 1;
    }

    // merge the two row-halves (lanes l and l+32 hold the same point's rows)
#pragma unroll
    for (int pb = 0; pb < 2; ++pb) {
        unsigned int b = best[pb], s = sec[pb];
        unsigned int ob = __shfl_xor(b, 32);
        unsigned int os = __shfl_xor(s, 32);
        s = min(min(s, os), max(b, ob));
        b = min(b, ob);
        if (lane < 32) {
            const int p = pbase + pb * 32 + lane;
            out[p] = (int)(b & 1023u);
            float bf = __uint_as_float(b & 0xFFFFFC00u);  // = acc_best (trunc), < 0
            float sf = __uint_as_float(s & 0xFFFFFC00u);  // = acc_sec  (trunc)
            // sign-check: b < 0x80000000 means acc >= 0 (key order unproven) -> refine
            if ((b < 0x80000000u) || (2.f * (bf - sf) < TAU_DIST)) {
                int sl = atomicAdd(counter, 1);
                if (sl < cap) list[sl] = p;
            }
        }
    }
}

// ---------------- refine2: exact fp32, round-1 chain order, LDS-tiled -------
// Wave-per-point (round-3 measured-good). Block = 4 waves; lane = center
// within 64-row tile; LDS stride 65 -> 2-way bank alias (free).
__launch_bounds__(256, 2)
__global__ void refine2_kernel(const float* __restrict__ x,
                               const float* __restrict__ centers,
                               const float* __restrict__ cn,
                               const int* __restrict__ list,
                               const int* __restrict__ counter,
                               int* __restrict__ out, int cap) {
    __shared__ float ldsC[64 * 65];   // 16.6 KiB
    int cnt = *counter; if (cnt > cap) cnt = cap;
    const int tid  = threadIdx.x;
    const int wv   = tid >> 6;
    const int lane = tid & 63;

#pragma unroll 1
    for (int base = blockIdx.x * 4; base < cnt; base += gridDim.x * 4) {
        const int i = base + wv;
        const bool valid = (i < cnt);
        const int p = valid ? list[i] : 0;

        const float4* xr = reinterpret_cast<const float4*>(x + (size_t)p * DIM);
        float4 xv[16];
        float xn0 = 0.f, xn1 = 0.f, xn2 = 0.f, xn3 = 0.f;
#pragma unroll
        for (int j = 0; j < 16; ++j) {
            float4 v = xr[j]; xv[j] = v;
            xn0 = fmaf(v.x, v.x, xn0); xn1 = fmaf(v.y, v.y, xn1);
            xn2 = fmaf(v.z, v.z, xn2); xn3 = fmaf(v.w, v.w, xn3);
        }
        const float xnv = (xn0 + xn1) + (xn2 + xn3);

        float bestv = 3.4e38f; int bi = 0;
#pragma unroll 1
        for (int t = 0; t < 16; ++t) {            // 16 tiles x 64 centers
            __syncthreads();
#pragma unroll
            for (int j = 0; j < 16; ++j) {
                int idx = j * 256 + tid;
                int row = idx >> 6, col = idx & 63;
                ldsC[row * 65 + col] = centers[((size_t)t * 64 + row) * DIM + col];
            }
            __syncthreads();
            if (valid) {
                const int k = t * 64 + lane;
                const float* cr = ldsC + lane * 65;
                float a0 = 0.f, a1 = 0.f, a2 = 0.f, a3 = 0.f;
#pragma unroll
                for (int jj = 0; jj < 16; ++jj) {
                    a0 = fmaf(xv[jj].x, cr[jj * 4 + 0], a0);
                    a1 = fmaf(xv[jj].y, cr[jj * 4 + 1], a1);
                    a2 = fmaf(xv[jj].z, cr[jj * 4 + 2], a2);
                    a3 = fmaf(xv[jj].w, cr[jj * 4 + 3], a3);
                }
                float dot  = (a0 + a1) + (a2 + a3);
                float dist = fabsf(fmaf(-2.f, dot, xnv + cn[k]));
                if (dist < bestv) { bestv = dist; bi = k; }
            }
        }
#pragma unroll
        for (int off = 1; off < 64; off <<= 1) {
            float ob = __shfl_xor(bestv, off);
            int   oi = __shfl_xor(bi, off);
            bool take = (ob < bestv) || (ob == bestv && oi < bi);
            bestv = take ? ob : bestv;
            bi    = take ? oi : bi;
        }
        if (valid && lane == 0) out[p] = bi;
    }
}

// ---------------- fallback: pure fp32 path (ws too small) ----------
#define TK 128
__launch_bounds__(256, 4)
__global__ void assign_fp32(const float* __restrict__ x,
                            const float* __restrict__ centers,
                            const float* __restrict__ cn,
                            int* __restrict__ out) {
    __shared__ float ldsC[TK * DIM];
    __shared__ float ldsN[TK];
    const int tid = threadIdx.x;
    const int p = blockIdx.x * 256 + tid;
    const float4* xr = reinterpret_cast<const float4*>(x + (size_t)p * DIM);
    float4 xv[16];
    float xn0 = 0.f, xn1 = 0.f, xn2 = 0.f, xn3 = 0.f;
#pragma unroll
    for (int j = 0; j < 16; ++j) {
        float4 v = xr[j]; xv[j] = v;
        xn0 = fmaf(v.x, v.x, xn0); xn1 = fmaf(v.y, v.y, xn1);
        xn2 = fmaf(v.z, v.z, xn2); xn3 = fmaf(v.w, v.w, xn3);
    }
    const float xn = (xn0 + xn1) + (xn2 + xn3);
    float bestv = 3.4e38f; int best = 0;
#pragma unroll 1
    for (int t = 0; t < K_CTR / TK; ++t) {
        __syncthreads();
        const float4* cg = reinterpret_cast<const float4*>(centers + (size_t)t * TK * DIM);
        float4* cl = reinterpret_cast<float4*>(ldsC);
#pragma unroll
        for (int j = 0; j < (TK * DIM / 4) / 256; ++j)
            cl[j * 256 + tid] = cg[j * 256 + tid];
        if (tid < TK) ldsN[tid] = cn[t * TK + tid];
        __syncthreads();
        for (int k = 0; k < TK; ++k) {
            const float4* cv = reinterpret_cast<const float4*>(ldsC + k * DIM);
            float a0 = 0.f, a1 = 0.f, a2 = 0.f, a3 = 0.f;
#pragma unroll
            for (int j = 0; j < 16; ++j) {
                float4 c4 = cv[j];
                a0 = fmaf(xv[j].x, c4.x, a0); a1 = fmaf(xv[j].y, c4.y, a1);
                a2 = fmaf(xv[j].z, c4.z, a2); a3 = fmaf(xv[j].w, c4.w, a3);
            }
            float dot = (a0 + a1) + (a2 + a3);
            float dist = fabsf(fmaf(-2.f, dot, xn + ldsN[k]));
            if (dist < bestv) { bestv = dist; best = t * TK + k; }
        }
    }
    out[p] = best;
}

extern "C" void kernel_launch(void* const* d_in, const int* in_sizes, int n_in,
                              void* d_out, int out_size, void* d_ws, size_t ws_size,
                              hipStream_t stream) {
    const float* x = (const float*)d_in[0];
    const float* centers = (const float*)d_in[1];
    int* out = (int*)d_out;
    char* ws = (char*)d_ws;
    float* cn = (float*)(ws + WS_CN);
    float* ci = (float*)(ws + WS_CI);
    unsigned short* hiG = (unsigned short*)(ws + WS_HI);
    unsigned short* loG = (unsigned short*)(ws + WS_LO);
    int* counter = (int*)(ws + WS_CTR);
    int* list = (int*)(ws + WS_LIST);

    if (ws_size >= WS_MIN) {
        size_t avail = (ws_size - WS_LIST) / sizeof(int);
        int cap = (int)(avail < (size_t)N_PTS ? avail : (size_t)N_PTS);
        prep_kernel<<<4, 256, 0, stream>>>(centers, cn, ci, counter);
        split_kernel<<<32, 256, 0, stream>>>(centers, hiG, loG);
        assign_mfma<<<N_PTS / 256, 256, 0, stream>>>(x, hiG, loG, ci, out, counter, list, cap);
        refine2_kernel<<<1024, 256, 0, stream>>>(x, centers, cn, list, counter, out, cap);
    } else {
        prep_kernel<<<4, 256, 0, stream>>>(centers, cn, ci, counter);
        assign_fp32<<<N_PTS / 256, 256, 0, stream>>>(x, centers, cn, out);
    }
}

// Round 18
// 117.685 us; speedup vs baseline: 1.1233x; 1.1233x over previous
//
#include <hip/hip_runtime.h>
#include <float.h>

// KMeans assign: N=262144, K=1024, D=64, fp32 in, int32 argmin out.
// Round 18: LOCK-IN of round 8 (best measured: 117.97us total; assign ~88us).
// Final structure after 11 probed alternatives (r7-r17: dbuf pipelining,
// setprio, barrier-free, occupancy 2-5 waves/SIMD, stagger+counted vmcnt,
// asm-pinned MFMA, SGB interleave, epilogue software-pipelining, 32x32x16):
// all null or regressions. Wall = MFMA-pipe (49.7us) + argmin-epilogue VALU
// (~33us) + staging residue; pipes don't overlap for same-code waves.
// Numerics (absmax=0 across 8 passing rounds): bf16x2 split (hh+hl+lh),
// acc init = -cn/2-OFFC folded into MFMA C (xn dropped: argmin-invariant),
// key-packed argmin (trunc-bits|idx, umin = first-index argmin), second-best
// gap flagging (TAU=0.05) + sign-check self-flag, refine2 = wave-per-point
// exact fp32 with round-1 summation order (empirically matches np).

#define N_PTS 262144
#define K_CTR 1024
#define DIM   64
#define CTILE 64          // centers per tile; 16 tiles; dbuf: 2x(8+8) KiB
#define NTILE (K_CTR / CTILE)
#define OFFC  32.0f
#define TAU_DIST 0.05f

// ws byte offsets
#define WS_CN    0          // f32[1024]
#define WS_CI    4096       // f32[1024]  cninit = -cn/2 - OFFC
#define WS_HI    8192       // ushort[8192*8]  frag-major hi  (128 KiB)
#define WS_LO    139264     // ushort[8192*8]  frag-major lo  (128 KiB)
#define WS_CTR   270336     // int counter
#define WS_LIST  270592     // int list[...]
#define WS_MIN   (270592 + 4 * 65536)

typedef __attribute__((ext_vector_type(8))) short  short8;
typedef __attribute__((ext_vector_type(8))) __bf16 bf16x8;
typedef __attribute__((ext_vector_type(4))) float  f32x4;

union FragU { short8 s; bf16x8 b; unsigned short u[8]; };

static __device__ __forceinline__ unsigned short bfbits(__bf16 h) {
    return __builtin_bit_cast(unsigned short, h);
}

#if defined(__has_builtin)
#if __has_builtin(__builtin_amdgcn_global_load_lds)
#define HAVE_GLD 1
#endif
#endif

#ifdef HAVE_GLD
#define GLD16(gsrc, ldst)                                                      \
    __builtin_amdgcn_global_load_lds(                                          \
        (const __attribute__((address_space(1))) void*)(gsrc),                 \
        (__attribute__((address_space(3))) void*)(ldst), 16, 0, 0)
#endif

// ---------------- prep: centers_norm (round-1 chain), cninit, counter=0 -----
__global__ void prep_kernel(const float* __restrict__ centers,
                            float* __restrict__ cn, float* __restrict__ ci,
                            int* __restrict__ counter) {
    int k = blockIdx.x * 256 + threadIdx.x;
    if (k == 0) *counter = 0;
    if (k < K_CTR) {
        const float4* c = reinterpret_cast<const float4*>(centers + (size_t)k * DIM);
        float s0 = 0.f, s1 = 0.f, s2 = 0.f, s3 = 0.f;
#pragma unroll
        for (int j = 0; j < 16; ++j) {
            float4 v = c[j];
            s0 = fmaf(v.x, v.x, s0); s1 = fmaf(v.y, v.y, s1);
            s2 = fmaf(v.z, v.z, s2); s3 = fmaf(v.w, v.w, s3);
        }
        float n = (s0 + s1) + (s2 + s3);
        cn[k] = n;
        ci[k] = fmaf(-0.5f, n, -OFFC);
    }
}

// ---------------- split: centers -> frag-major bf16 hi/lo (once) ------------
// slot si in [0,8192): lane=si&63, ks=(si>>6)&1, st=(si>>7)&3, tile=si>>9;
// center row = tile*64 + st*16 + (lane&15); dims = ks*32 + ((lane>>4)&3)*8.
__global__ void split_kernel(const float* __restrict__ centers,
                             unsigned short* __restrict__ hiG,
                             unsigned short* __restrict__ loG) {
    int si = blockIdx.x * 256 + threadIdx.x;   // 8192 total
    int lane = si & 63, ks = (si >> 6) & 1, st = (si >> 7) & 3, tile = si >> 9;
    int row = tile * CTILE + st * 16 + (lane & 15);
    int dimb = ks * 32 + ((lane >> 4) & 3) * 8;
    const float* g = centers + (size_t)row * DIM + dimb;
    float4 v0 = *reinterpret_cast<const float4*>(g);
    float4 v1 = *reinterpret_cast<const float4*>(g + 4);
    float vv[8] = {v0.x, v0.y, v0.z, v0.w, v1.x, v1.y, v1.z, v1.w};
    FragU hi, lo;
#pragma unroll
    for (int j = 0; j < 8; ++j) {
        __bf16 h = (__bf16)vv[j];
        hi.u[j] = bfbits(h);
        lo.u[j] = bfbits((__bf16)(vv[j] - (float)h));
    }
    *reinterpret_cast<short8*>(hiG + (size_t)si * 8) = hi.s;
    *reinterpret_cast<short8*>(loG + (size_t)si * 8) = lo.s;
}

// ---------------- main: MFMA assign, pipelined double-buffer ----------------
__launch_bounds__(256, 2)
__global__ void assign_mfma(const float* __restrict__ x,
                            const unsigned short* __restrict__ hiG,
                            const unsigned short* __restrict__ loG,
                            const float* __restrict__ ci,
                            int* __restrict__ out,
                            int* __restrict__ counter,
                            int* __restrict__ list, int cap) {
    __shared__ __align__(16) unsigned short lh[2 * 512 * 8];  // 16 KiB (2 buf)
    __shared__ __align__(16) unsigned short ll[2 * 512 * 8];  // 16 KiB (2 buf)
    __shared__ __align__(16) float ciL[K_CTR];                // 4 KiB

    const int tid  = threadIdx.x;
    const int wv   = tid >> 6;
    const int lane = tid & 63;
    const int g    = lane >> 4;
    const int lr   = lane & 15;
    const int pbase = blockIdx.x * 256 + wv * 64;

#pragma unroll
    for (int j = 0; j < 4; ++j) ciL[j * 256 + tid] = ci[j * 256 + tid];

    // B fragments (points): bf16 hi/lo, [colblock][kstep]
    bf16x8 bh[4][2], bl[4][2];
#pragma unroll
    for (int cb = 0; cb < 4; ++cb) {
        const int p = pbase + cb * 16 + lr;
        const float* xr = x + (size_t)p * DIM + g * 8;
        float4 v0 = *reinterpret_cast<const float4*>(xr);
        float4 v1 = *reinterpret_cast<const float4*>(xr + 4);
        float4 v2 = *reinterpret_cast<const float4*>(xr + 32);
        float4 v3 = *reinterpret_cast<const float4*>(xr + 36);
        float vv[16] = {v0.x, v0.y, v0.z, v0.w, v1.x, v1.y, v1.z, v1.w,
                        v2.x, v2.y, v2.z, v2.w, v3.x, v3.y, v3.z, v3.w};
#pragma unroll
        for (int j = 0; j < 16; ++j) {
            __bf16 hb = (__bf16)vv[j];
            bh[cb][j >> 3][j & 7] = hb;
            bl[cb][j >> 3][j & 7] = (__bf16)(vv[j] - (float)hb);
        }
    }

    unsigned int best[4], sec[4];
#pragma unroll
    for (int cb = 0; cb < 4; ++cb) { best[cb] = 0xFFFFFFFFu; sec[cb] = 0xFFFFFFFFu; }

    // ---- staging helper: 512 hi + 512 lo slots per tile, 2+2 GLD16/thread
#define STAGE(buf, tile)                                                       \
    do {                                                                       \
        const size_t sb = (size_t)((tile) * 512 + wv * 64 + lane) * 8;         \
        unsigned short* dh = lh + ((buf) * 512 + wv * 64) * 8;                 \
        unsigned short* dl = ll + ((buf) * 512 + wv * 64) * 8;                 \
        GLD16(hiG + sb, dh);                                                   \
        GLD16(hiG + sb + 256 * 8, dh + 256 * 8);                               \
        GLD16(loG + sb, dl);                                                   \
        GLD16(loG + sb + 256 * 8, dl + 256 * 8);                               \
    } while (0)

#ifndef HAVE_GLD
#undef STAGE
#define STAGE(buf, tile)                                                       \
    do {                                                                       \
        const short8* hs = reinterpret_cast<const short8*>(hiG) + (tile) * 512; \
        const short8* ls = reinterpret_cast<const short8*>(loG) + (tile) * 512; \
        short8* hd = reinterpret_cast<short8*>(lh) + (buf) * 512;              \
        short8* ld = reinterpret_cast<short8*>(ll) + (buf) * 512;              \
        hd[tid] = hs[tid]; hd[256 + tid] = hs[256 + tid];                      \
        ld[tid] = ls[tid]; ld[256 + tid] = ls[256 + tid];                      \
    } while (0)
#endif

    // prologue: stage tile 0 into buf 0
    STAGE(0, 0);
    __syncthreads();

    int cur = 0;
#pragma unroll 1
    for (int tile = 0; tile < NTILE; ++tile) {
        if (tile < NTILE - 1) STAGE(cur ^ 1, tile + 1);   // issue BEFORE compute

        const char* lhc = (const char*)lh + cur * 512 * 16 + lane * 16;
        const char* llc = (const char*)ll + cur * 512 * 16 + lane * 16;
        const unsigned int ibt = tile * CTILE + g * 4;
        const float* cib = ciL + tile * CTILE + g * 4;

#pragma unroll
        for (int st = 0; st < CTILE / 16; ++st) {
            FragU ah0, ah1, al0, al1;
            ah0.s = *reinterpret_cast<const short8*>(lhc + st * 2048);
            ah1.s = *reinterpret_cast<const short8*>(lhc + st * 2048 + 1024);
            al0.s = *reinterpret_cast<const short8*>(llc + st * 2048);
            al1.s = *reinterpret_cast<const short8*>(llc + st * 2048 + 1024);
            const f32x4 init4 = *reinterpret_cast<const f32x4*>(cib + st * 16);

            f32x4 acc[4];
            __builtin_amdgcn_s_setprio(1);
#pragma unroll
            for (int cb = 0; cb < 4; ++cb)
                acc[cb] = __builtin_amdgcn_mfma_f32_16x16x32_bf16(ah0.b, bh[cb][0], init4, 0, 0, 0);
#pragma unroll
            for (int cb = 0; cb < 4; ++cb)
                acc[cb] = __builtin_amdgcn_mfma_f32_16x16x32_bf16(ah0.b, bl[cb][0], acc[cb], 0, 0, 0);
#pragma unroll
            for (int cb = 0; cb < 4; ++cb)
                acc[cb] = __builtin_amdgcn_mfma_f32_16x16x32_bf16(al0.b, bh[cb][0], acc[cb], 0, 0, 0);
#pragma unroll
            for (int cb = 0; cb < 4; ++cb)
                acc[cb] = __builtin_amdgcn_mfma_f32_16x16x32_bf16(ah1.b, bh[cb][1], acc[cb], 0, 0, 0);
#pragma unroll
            for (int cb = 0; cb < 4; ++cb)
                acc[cb] = __builtin_amdgcn_mfma_f32_16x16x32_bf16(ah1.b, bl[cb][1], acc[cb], 0, 0, 0);
#pragma unroll
            for (int cb = 0; cb < 4; ++cb)
                acc[cb] = __builtin_amdgcn_mfma_f32_16x16x32_bf16(al1.b, bh[cb][1], acc[cb], 0, 0, 0);
            __builtin_amdgcn_s_setprio(0);

            unsigned int vidx[4];
            vidx[0] = ibt + st * 16;
            vidx[1] = vidx[0] + 1; vidx[2] = vidx[0] + 2; vidx[3] = vidx[0] + 3;

#pragma unroll
            for (int cb = 0; cb < 4; ++cb) {
#pragma unroll
                for (int pr = 0; pr < 2; ++pr) {
                    unsigned int ka = (__float_as_uint(acc[cb][pr * 2 + 0]) & 0xFFFFFC00u) | vidx[pr * 2 + 0];
                    unsigned int kb = (__float_as_uint(acc[cb][pr * 2 + 1]) & 0xFFFFFC00u) | vidx[pr * 2 + 1];
                    unsigned int bo = best[cb], med, bn;
                    asm("v_med3_u32 %0, %1, %2, %3" : "=v"(med) : "v"(ka), "v"(kb), "v"(bo));
                    asm("v_min3_u32 %0, %1, %2, %3" : "=v"(bn)  : "v"(ka), "v"(kb), "v"(bo));
                    best[cb] = bn;
                    sec[cb]  = min(sec[cb], med);
                }
            }
        }

        __syncthreads();   // vmcnt(0)+barrier: stage(tile+1) landed, buf[cur] free
        cur ^= 1;
    }

    // merge the 4 disjoint k-groups per point
#pragma unroll
    for (int cb = 0; cb < 4; ++cb) {
        unsigned int b = best[cb], s = sec[cb];
#pragma unroll
        for (int off = 16; off <= 32; off <<= 1) {
            unsigned int ob = __shfl_xor(b, off);
            unsigned int os = __shfl_xor(s, off);
            s = min(min(s, os), max(b, ob));
            b = min(b, ob);
        }
        if (g == 0) {
            const int p = pbase + cb * 16 + lr;
            out[p] = (int)(b & 1023u);
            float bf = __uint_as_float(b & 0xFFFFFC00u);  // = acc_best (trunc), < 0
            float sf = __uint_as_float(s & 0xFFFFFC00u);  // = acc_sec  (trunc)
            // sign-check: b < 0x80000000 means acc >= 0 (key order unproven) -> refine
            if ((b < 0x80000000u) || (2.f * (bf - sf) < TAU_DIST)) {
                int sl = atomicAdd(counter, 1);
                if (sl < cap) list[sl] = p;
            }
        }
    }
}

// ---------------- refine2: exact fp32, round-1 chain order, LDS-tiled -------
// Wave-per-point (round-3 measured-good). Block = 4 waves; lane = center
// within 64-row tile; LDS stride 65 -> 2-way bank alias (free).
__launch_bounds__(256, 2)
__global__ void refine2_kernel(const float* __restrict__ x,
                               const float* __restrict__ centers,
                               const float* __restrict__ cn,
                               const int* __restrict__ list,
                               const int* __restrict__ counter,
                               int* __restrict__ out, int cap) {
    __shared__ float ldsC[64 * 65];   // 16.6 KiB
    int cnt = *counter; if (cnt > cap) cnt = cap;
    const int tid  = threadIdx.x;
    const int wv   = tid >> 6;
    const int lane = tid & 63;

#pragma unroll 1
    for (int base = blockIdx.x * 4; base < cnt; base += gridDim.x * 4) {
        const int i = base + wv;
        const bool valid = (i < cnt);
        const int p = valid ? list[i] : 0;

        const float4* xr = reinterpret_cast<const float4*>(x + (size_t)p * DIM);
        float4 xv[16];
        float xn0 = 0.f, xn1 = 0.f, xn2 = 0.f, xn3 = 0.f;
#pragma unroll
        for (int j = 0; j < 16; ++j) {
            float4 v = xr[j]; xv[j] = v;
            xn0 = fmaf(v.x, v.x, xn0); xn1 = fmaf(v.y, v.y, xn1);
            xn2 = fmaf(v.z, v.z, xn2); xn3 = fmaf(v.w, v.w, xn3);
        }
        const float xnv = (xn0 + xn1) + (xn2 + xn3);

        float bestv = 3.4e38f; int bi = 0;
#pragma unroll 1
        for (int t = 0; t < 16; ++t) {            // 16 tiles x 64 centers
            __syncthreads();
#pragma unroll
            for (int j = 0; j < 16; ++j) {
                int idx = j * 256 + tid;
                int row = idx >> 6, col = idx & 63;
                ldsC[row * 65 + col] = centers[((size_t)t * 64 + row) * DIM + col];
            }
            __syncthreads();
            if (valid) {
                const int k = t * 64 + lane;
                const float* cr = ldsC + lane * 65;
                float a0 = 0.f, a1 = 0.f, a2 = 0.f, a3 = 0.f;
#pragma unroll
                for (int jj = 0; jj < 16; ++jj) {
                    a0 = fmaf(xv[jj].x, cr[jj * 4 + 0], a0);
                    a1 = fmaf(xv[jj].y, cr[jj * 4 + 1], a1);
                    a2 = fmaf(xv[jj].z, cr[jj * 4 + 2], a2);
                    a3 = fmaf(xv[jj].w, cr[jj * 4 + 3], a3);
                }
                float dot  = (a0 + a1) + (a2 + a3);
                float dist = fabsf(fmaf(-2.f, dot, xnv + cn[k]));
                if (dist < bestv) { bestv = dist; bi = k; }
            }
        }
#pragma unroll
        for (int off = 1; off < 64; off <<= 1) {
            float ob = __shfl_xor(bestv, off);
            int   oi = __shfl_xor(bi, off);
            bool take = (ob < bestv) || (ob == bestv && oi < bi);
            bestv = take ? ob : bestv;
            bi    = take ? oi : bi;
        }
        if (valid && lane == 0) out[p] = bi;
    }
}

// ---------------- fallback: pure fp32 path (ws too small) ----------
#define TK 128
__launch_bounds__(256, 4)
__global__ void assign_fp32(const float* __restrict__ x,
                            const float* __restrict__ centers,
                            const float* __restrict__ cn,
                            int* __restrict__ out) {
    __shared__ float ldsC[TK * DIM];
    __shared__ float ldsN[TK];
    const int tid = threadIdx.x;
    const int p = blockIdx.x * 256 + tid;
    const float4* xr = reinterpret_cast<const float4*>(x + (size_t)p * DIM);
    float4 xv[16];
    float xn0 = 0.f, xn1 = 0.f, xn2 = 0.f, xn3 = 0.f;
#pragma unroll
    for (int j = 0; j < 16; ++j) {
        float4 v = xr[j]; xv[j] = v;
        xn0 = fmaf(v.x, v.x, xn0); xn1 = fmaf(v.y, v.y, xn1);
        xn2 = fmaf(v.z, v.z, xn2); xn3 = fmaf(v.w, v.w, xn3);
    }
    const float xn = (xn0 + xn1) + (xn2 + xn3);
    float bestv = 3.4e38f; int best = 0;
#pragma unroll 1
    for (int t = 0; t < K_CTR / TK; ++t) {
        __syncthreads();
        const float4* cg = reinterpret_cast<const float4*>(centers + (size_t)t * TK * DIM);
        float4* cl = reinterpret_cast<float4*>(ldsC);
#pragma unroll
        for (int j = 0; j < (TK * DIM / 4) / 256; ++j)
            cl[j * 256 + tid] = cg[j * 256 + tid];
        if (tid < TK) ldsN[tid] = cn[t * TK + tid];
        __syncthreads();
        for (int k = 0; k < TK; ++k) {
            const float4* cv = reinterpret_cast<const float4*>(ldsC + k * DIM);
            float a0 = 0.f, a1 = 0.f, a2 = 0.f, a3 = 0.f;
#pragma unroll
            for (int j = 0; j < 16; ++j) {
                float4 c4 = cv[j];
                a0 = fmaf(xv[j].x, c4.x, a0); a1 = fmaf(xv[j].y, c4.y, a1);
                a2 = fmaf(xv[j].z, c4.z, a2); a3 = fmaf(xv[j].w, c4.w, a3);
            }
            float dot = (a0 + a1) + (a2 + a3);
            float dist = fabsf(fmaf(-2.f, dot, xn + ldsN[k]));
            if (dist < bestv) { bestv = dist; best = t * TK + k; }
        }
    }
    out[p] = best;
}

extern "C" void kernel_launch(void* const* d_in, const int* in_sizes, int n_in,
                              void* d_out, int out_size, void* d_ws, size_t ws_size,
                              hipStream_t stream) {
    const float* x = (const float*)d_in[0];
    const float* centers = (const float*)d_in[1];
    int* out = (int*)d_out;
    char* ws = (char*)d_ws;
    float* cn = (float*)(ws + WS_CN);
    float* ci = (float*)(ws + WS_CI);
    unsigned short* hiG = (unsigned short*)(ws + WS_HI);
    unsigned short* loG = (unsigned short*)(ws + WS_LO);
    int* counter = (int*)(ws + WS_CTR);
    int* list = (int*)(ws + WS_LIST);

    if (ws_size >= WS_MIN) {
        size_t avail = (ws_size - WS_LIST) / sizeof(int);
        int cap = (int)(avail < (size_t)N_PTS ? avail : (size_t)N_PTS);
        prep_kernel<<<4, 256, 0, stream>>>(centers, cn, ci, counter);
        split_kernel<<<32, 256, 0, stream>>>(centers, hiG, loG);
        assign_mfma<<<N_PTS / 256, 256, 0, stream>>>(x, hiG, loG, ci, out, counter, list, cap);
        refine2_kernel<<<1024, 256, 0, stream>>>(x, centers, cn, list, counter, out, cap);
    } else {
        prep_kernel<<<4, 256, 0, stream>>>(centers, cn, ci, counter);
        assign_fp32<<<N_PTS / 256, 256, 0, stream>>>(x, centers, cn, out);
    }
}